// Round 1
// baseline (428.947 us; speedup 1.0000x reference)
//
#include <hip/hip_runtime.h>
#include <cstdint>

// Problem constants (fixed by setup_inputs)
#define B_ 4
#define SQ_ 2048
#define ST_ 2048
#define E_ 512
#define H_ 8
#define HD_ 64

typedef _Float16 f16_t;
typedef _Float16 f16x8 __attribute__((ext_vector_type(8)));
typedef _Float16 f16x4 __attribute__((ext_vector_type(4)));
typedef float f32x4 __attribute__((ext_vector_type(4)));

static __device__ __forceinline__ f16x8 ld8(const f16_t* p) {
  return *reinterpret_cast<const f16x8*>(p);
}

// ---------------- fp32 -> fp16 cast (vectorized) ----------------
__global__ __launch_bounds__(256) void cast_f16_kernel(const float* __restrict__ in,
                                                       f16_t* __restrict__ out, int n4) {
  int i = blockIdx.x * 256 + threadIdx.x;
  if (i < n4) {
    float4 v = reinterpret_cast<const float4*>(in)[i];
    f16x4 o = {(f16_t)v.x, (f16_t)v.y, (f16_t)v.z, (f16_t)v.w};
    reinterpret_cast<f16x4*>(out)[i] = o;
  }
}

// ------------- weight transpose + cast: Wt[n][k] = (f16)W[k][n] -------------
__global__ __launch_bounds__(256) void wtrans_kernel(const float* __restrict__ W,
                                                     f16_t* __restrict__ Wt) {
  __shared__ float tile[32][33];
  const int tx = threadIdx.x & 31;
  const int ty = threadIdx.x >> 5;  // 0..7
  const int bx = blockIdx.x * 32;   // n block
  const int by = blockIdx.y * 32;   // k block
#pragma unroll
  for (int i = 0; i < 4; ++i)
    tile[ty + i * 8][tx] = W[(size_t)(by + ty + i * 8) * E_ + bx + tx];
  __syncthreads();
#pragma unroll
  for (int i = 0; i < 4; ++i)
    Wt[(size_t)(bx + ty + i * 8) * E_ + by + tx] = (f16_t)tile[tx][ty + i * 8];
}

// ------------- V transpose per head: VT[(bh*64+d)*ST + t] = V[(b*ST+t)*E + h*64+d] ---
__global__ __launch_bounds__(256) void vtrans_kernel(const f16_t* __restrict__ V,
                                                     f16_t* __restrict__ VT) {
  __shared__ f16_t tile[64][72];
  const int bh = blockIdx.y;
  const int b = bh >> 3, h = bh & 7;
  const int t0 = blockIdx.x * 64;
  for (int i = threadIdx.x; i < 64 * 64; i += 256) {
    const int t = i >> 6, d = i & 63;
    tile[d][t] = V[(size_t)(b * ST_ + t0 + t) * E_ + h * HD_ + d];
  }
  __syncthreads();
  for (int i = threadIdx.x; i < 64 * 64; i += 256) {
    const int d = i >> 6, t = i & 63;
    VT[(size_t)(bh * HD_ + d) * ST_ + t0 + t] = tile[d][t];
  }
}

// ------------- GEMM: C[m,n] = sum_k A[m,k] * Bt[n,k]  (128x128 tile, BK=32) -------------
// 4 waves, each wave 64x64 subtile as 4x4 frags of 16x16x32 f16 MFMA.
template <bool OUT_F16>
__global__ __launch_bounds__(256) void gemm_bt_kernel(const f16_t* __restrict__ A,
                                                      const f16_t* __restrict__ Bt,
                                                      void* __restrict__ Cv,
                                                      int M, int N, int K) {
  // pad to 40 elems (80B): keeps 16B alignment for b128, spreads banks
  __shared__ f16_t As[128][40];
  __shared__ f16_t Bs[128][40];
  const int tid = threadIdx.x;
  const int lane = tid & 63;
  const int wave = tid >> 6;
  const int wm = (wave >> 1) * 64;
  const int wn = (wave & 1) * 64;
  const int m0 = blockIdx.y * 128;
  const int n0 = blockIdx.x * 128;
  const int l16 = lane & 15;
  const int quad = lane >> 4;
  const int r0 = tid >> 2;         // 0..63: staging row
  const int c0 = (tid & 3) * 8;    // staging col (elements)

  f32x4 acc[4][4] = {};

  const f16_t* A0 = A + (size_t)(m0 + r0) * K + c0;
  const f16_t* A1 = A + (size_t)(m0 + 64 + r0) * K + c0;
  const f16_t* B0 = Bt + (size_t)(n0 + r0) * K + c0;
  const f16_t* B1 = Bt + (size_t)(n0 + 64 + r0) * K + c0;

  for (int k0 = 0; k0 < K; k0 += 32) {
    f16x8 a0 = ld8(A0 + k0);
    f16x8 a1 = ld8(A1 + k0);
    f16x8 b0 = ld8(B0 + k0);
    f16x8 b1 = ld8(B1 + k0);
    __syncthreads();  // protect previous iteration's fragment reads
    *reinterpret_cast<f16x8*>(&As[r0][c0]) = a0;
    *reinterpret_cast<f16x8*>(&As[64 + r0][c0]) = a1;
    *reinterpret_cast<f16x8*>(&Bs[r0][c0]) = b0;
    *reinterpret_cast<f16x8*>(&Bs[64 + r0][c0]) = b1;
    __syncthreads();
    f16x8 af[4], bfr[4];
#pragma unroll
    for (int i = 0; i < 4; ++i) af[i] = ld8(&As[wm + i * 16 + l16][quad * 8]);
#pragma unroll
    for (int j = 0; j < 4; ++j) bfr[j] = ld8(&Bs[wn + j * 16 + l16][quad * 8]);
#pragma unroll
    for (int i = 0; i < 4; ++i)
#pragma unroll
      for (int j = 0; j < 4; ++j)
        acc[i][j] = __builtin_amdgcn_mfma_f32_16x16x32_f16(af[i], bfr[j], acc[i][j], 0, 0, 0);
  }

#pragma unroll
  for (int i = 0; i < 4; ++i)
#pragma unroll
    for (int r = 0; r < 4; ++r) {
      const size_t row = (size_t)m0 + wm + i * 16 + quad * 4 + r;
#pragma unroll
      for (int j = 0; j < 4; ++j) {
        const size_t col = (size_t)n0 + wn + j * 16 + l16;
        if (OUT_F16)
          reinterpret_cast<f16_t*>(Cv)[row * (size_t)N + col] = (f16_t)acc[i][j][r];
        else
          reinterpret_cast<float*>(Cv)[row * (size_t)N + col] = acc[i][j][r];
      }
    }
}

// ------------- Flash attention: 64 q-rows/block (16/wave), T-tile 64 -------------
// Q,K: [B*S, E] f16 (head h at col h*64). VT: [B*H*64, ST]. bias: [SQ,ST] f16. O: [B*SQ,E] f16.
__global__ __launch_bounds__(256) void attn_kernel(const f16_t* __restrict__ Q,
                                                   const f16_t* __restrict__ K,
                                                   const f16_t* __restrict__ VT,
                                                   const f16_t* __restrict__ bias,
                                                   f16_t* __restrict__ O) {
  __shared__ f16_t Ps[4][16][72];  // per-wave P tile [16 q][64 t], pad 72
  const int bh = blockIdx.y;
  const int b = bh >> 3, h = bh & 7;
  const int q0 = blockIdx.x * 64;
  const int wave = threadIdx.x >> 6;
  const int lane = threadIdx.x & 63;
  const int l16 = lane & 15;
  const int quad = lane >> 4;
  const int qw = q0 + wave * 16;

  // Q fragments: A[m=l16][k=quad*8+j], two K=32 chunks covering hd=64
  const f16_t* qptr = Q + (size_t)(b * SQ_ + qw + l16) * E_ + h * HD_ + quad * 8;
  const f16x8 aq0 = ld8(qptr);
  const f16x8 aq1 = ld8(qptr + 32);

  f32x4 facc[4] = {};
  float m_i[4] = {-3.0e38f, -3.0e38f, -3.0e38f, -3.0e38f};
  float l_i[4] = {0.f, 0.f, 0.f, 0.f};
  const float scale = 0.125f;  // 1/sqrt(64)
  const float L2E = 1.44269504089f;

  const f16_t* kbase = K + (size_t)(b * ST_) * E_ + h * HD_ + quad * 8;
  const f16_t* vbase = VT + (size_t)(bh * HD_) * ST_;
  const f16_t* bias_row = bias + (size_t)(qw + quad * 4) * ST_ + l16;

  for (int t0 = 0; t0 < ST_; t0 += 64) {
    // S = Q K^T (C-layout: row=q offset quad*4+r, col=t offset l16)
    f32x4 s[4];
#pragma unroll
    for (int tt = 0; tt < 4; ++tt) {
      const f16_t* kp = kbase + (size_t)(t0 + tt * 16 + l16) * E_;
      f32x4 a = {};
      a = __builtin_amdgcn_mfma_f32_16x16x32_f16(aq0, ld8(kp), a, 0, 0, 0);
      a = __builtin_amdgcn_mfma_f32_16x16x32_f16(aq1, ld8(kp + 32), a, 0, 0, 0);
      s[tt] = a;
    }
#pragma unroll
    for (int tt = 0; tt < 4; ++tt)
#pragma unroll
      for (int r = 0; r < 4; ++r)
        s[tt][r] = s[tt][r] * scale + (float)bias_row[(size_t)r * ST_ + t0 + tt * 16];

    // online softmax: row max over 4 frags + 16-lane butterfly
    float alpha[4];
#pragma unroll
    for (int r = 0; r < 4; ++r) {
      float mx = fmaxf(fmaxf(s[0][r], s[1][r]), fmaxf(s[2][r], s[3][r]));
      mx = fmaxf(mx, __shfl_xor(mx, 1));
      mx = fmaxf(mx, __shfl_xor(mx, 2));
      mx = fmaxf(mx, __shfl_xor(mx, 4));
      mx = fmaxf(mx, __shfl_xor(mx, 8));
      const float mnew = fmaxf(m_i[r], mx);
      alpha[r] = exp2f((m_i[r] - mnew) * L2E);
      m_i[r] = mnew;
    }
    float rs[4] = {0.f, 0.f, 0.f, 0.f};
#pragma unroll
    for (int tt = 0; tt < 4; ++tt)
#pragma unroll
      for (int r = 0; r < 4; ++r) {
        const float p = exp2f((s[tt][r] - m_i[r]) * L2E);
        rs[r] += p;
        Ps[wave][quad * 4 + r][tt * 16 + l16] = (f16_t)p;  // per-wave region: no barrier
      }
#pragma unroll
    for (int r = 0; r < 4; ++r) {
      float t = rs[r];
      t += __shfl_xor(t, 1);
      t += __shfl_xor(t, 2);
      t += __shfl_xor(t, 4);
      t += __shfl_xor(t, 8);
      l_i[r] = l_i[r] * alpha[r] + t;
#pragma unroll
      for (int j = 0; j < 4; ++j) facc[j][r] *= alpha[r];
    }
    // O += P V : A = P from LDS (A-layout), B = V from VT (k=t contiguous)
#pragma unroll
    for (int tc = 0; tc < 2; ++tc) {
      const f16x8 ap = ld8(&Ps[wave][l16][tc * 32 + quad * 8]);
#pragma unroll
      for (int j = 0; j < 4; ++j) {
        const f16x8 bv = ld8(vbase + (size_t)(j * 16 + l16) * ST_ + t0 + tc * 32 + quad * 8);
        facc[j] = __builtin_amdgcn_mfma_f32_16x16x32_f16(ap, bv, facc[j], 0, 0, 0);
      }
    }
  }

#pragma unroll
  for (int r = 0; r < 4; ++r) {
    const float inv = 1.0f / l_i[r];
    f16_t* op = O + (size_t)(b * SQ_ + qw + quad * 4 + r) * E_ + h * HD_ + l16;
#pragma unroll
    for (int j = 0; j < 4; ++j) op[j * 16] = (f16_t)(facc[j][r] * inv);
  }
}

// ---------------- host launch ----------------
extern "C" void kernel_launch(void* const* d_in, const int* in_sizes, int n_in,
                              void* d_out, int out_size, void* d_ws, size_t ws_size,
                              hipStream_t stream) {
  (void)in_sizes; (void)n_in; (void)out_size; (void)ws_size;
  const float* query = (const float*)d_in[0];
  const float* target = (const float*)d_in[1];
  const float* bias = (const float*)d_in[2];
  const float* Wq = (const float*)d_in[3];
  const float* Wk = (const float*)d_in[4];
  const float* Wv = (const float*)d_in[5];
  const float* Wo = (const float*)d_in[6];

  char* ws = (char*)d_ws;
  const size_t ACT = (size_t)B_ * SQ_ * E_;           // 4,194,304 elements
  const size_t ACT_B = ACT * sizeof(f16_t);           // 8 MB
  const size_t BIAS_B = (size_t)SQ_ * ST_ * sizeof(f16_t);  // 8 MB
  const size_t W_B = (size_t)E_ * E_ * sizeof(f16_t);       // 512 KB

  f16_t* qb = (f16_t*)(ws);                       // query f16; reused as VT later
  f16_t* tb = (f16_t*)(ws + ACT_B);               // target f16
  f16_t* biasb = (f16_t*)(ws + 2 * ACT_B);        // bias f16
  f16_t* WqT = (f16_t*)(ws + 2 * ACT_B + BIAS_B);
  f16_t* WkT = WqT + (size_t)E_ * E_;
  f16_t* WvT = WkT + (size_t)E_ * E_;
  f16_t* WoT = WvT + (size_t)E_ * E_;
  f16_t* Qp = (f16_t*)(ws + 2 * ACT_B + BIAS_B + 4 * W_B);
  f16_t* Kp = Qp + ACT;
  f16_t* Vp = Kp + ACT;
  f16_t* VT = qb;    // qb dead after Q projection
  f16_t* attn = Vp;  // Vp dead after vtrans
  // total ws: 50.3 MB

  const int n4_act = (int)(ACT / 4);
  const int n4_bias = SQ_ * ST_ / 4;
  dim3 blk(256);
  cast_f16_kernel<<<dim3((n4_act + 255) / 256), blk, 0, stream>>>(query, qb, n4_act);
  cast_f16_kernel<<<dim3((n4_act + 255) / 256), blk, 0, stream>>>(target, tb, n4_act);
  cast_f16_kernel<<<dim3((n4_bias + 255) / 256), blk, 0, stream>>>(bias, biasb, n4_bias);
  dim3 wgrid(E_ / 32, E_ / 32);
  wtrans_kernel<<<wgrid, blk, 0, stream>>>(Wq, WqT);
  wtrans_kernel<<<wgrid, blk, 0, stream>>>(Wk, WkT);
  wtrans_kernel<<<wgrid, blk, 0, stream>>>(Wv, WvT);
  wtrans_kernel<<<wgrid, blk, 0, stream>>>(Wo, WoT);

  dim3 ggrid(E_ / 128, B_ * SQ_ / 128);  // (4, 64)
  gemm_bt_kernel<true><<<ggrid, blk, 0, stream>>>(qb, WqT, Qp, B_ * SQ_, E_, E_);
  gemm_bt_kernel<true><<<ggrid, blk, 0, stream>>>(tb, WkT, Kp, B_ * SQ_, E_, E_);
  gemm_bt_kernel<true><<<ggrid, blk, 0, stream>>>(tb, WvT, Vp, B_ * SQ_, E_, E_);

  vtrans_kernel<<<dim3(ST_ / 64, B_ * H_), blk, 0, stream>>>(Vp, VT);

  attn_kernel<<<dim3(SQ_ / 64, B_ * H_), blk, 0, stream>>>(Qp, Kp, VT, biasb, attn);

  gemm_bt_kernel<false><<<ggrid, blk, 0, stream>>>(attn, WoT, (void*)d_out, B_ * SQ_, E_, E_);
}

// Round 2
// 322.778 us; speedup vs baseline: 1.3289x; 1.3289x over previous
//
#include <hip/hip_runtime.h>
#include <cstdint>

// Problem constants (fixed by setup_inputs)
#define B_ 4
#define SQ_ 2048
#define ST_ 2048
#define E_ 512
#define H_ 8
#define HD_ 64

typedef _Float16 f16_t;
typedef _Float16 f16x8 __attribute__((ext_vector_type(8)));
typedef _Float16 f16x4 __attribute__((ext_vector_type(4)));
typedef float f32x4 __attribute__((ext_vector_type(4)));

static __device__ __forceinline__ f16x8 ld8(const f16_t* p) {
  return *reinterpret_cast<const f16x8*>(p);
}

// ---------------- fp32 -> fp16 cast (vectorized) ----------------
__global__ __launch_bounds__(256) void cast_f16_kernel(const float* __restrict__ in,
                                                       f16_t* __restrict__ out, int n4) {
  int i = blockIdx.x * 256 + threadIdx.x;
  if (i < n4) {
    float4 v = reinterpret_cast<const float4*>(in)[i];
    f16x4 o = {(f16_t)v.x, (f16_t)v.y, (f16_t)v.z, (f16_t)v.w};
    reinterpret_cast<f16x4*>(out)[i] = o;
  }
}

// ------------- weight transpose + cast: Wt[n][k] = (f16)W[k][n] -------------
__global__ __launch_bounds__(256) void wtrans_kernel(const float* __restrict__ W,
                                                     f16_t* __restrict__ Wt) {
  __shared__ float tile[32][33];
  const int tx = threadIdx.x & 31;
  const int ty = threadIdx.x >> 5;  // 0..7
  const int bx = blockIdx.x * 32;   // n block
  const int by = blockIdx.y * 32;   // k block
#pragma unroll
  for (int i = 0; i < 4; ++i)
    tile[ty + i * 8][tx] = W[(size_t)(by + ty + i * 8) * E_ + bx + tx];
  __syncthreads();
#pragma unroll
  for (int i = 0; i < 4; ++i)
    Wt[(size_t)(bx + ty + i * 8) * E_ + by + tx] = (f16_t)tile[tx][ty + i * 8];
}

// ------------- bias rearrange into MFMA C-fragment order (f16) -------------
// biasR f16x4 index: ((q>>4)*128 + (t>>4))*64 + ((q>>2)&3)*16 + (t&15), elem r = q&3
__global__ __launch_bounds__(256) void bias_rearrange_kernel(const float* __restrict__ bias,
                                                             f16x4* __restrict__ biasR) {
  __shared__ float tile[64][65];
  const int q0 = blockIdx.y * 64;
  const int t0 = blockIdx.x * 64;
  const int tid = threadIdx.x;
  for (int i = tid; i < 64 * 64; i += 256) {
    const int q = i >> 6, t = i & 63;
    tile[q][t] = bias[(size_t)(q0 + q) * ST_ + t0 + t];
  }
  __syncthreads();
#pragma unroll
  for (int s = 0; s < 4; ++s) {
    const int slot = s * 256 + tid;        // 0..1023
    const int tile_id = slot >> 6;         // 0..15
    const int lane = slot & 63;
    const int tq = tile_id >> 2, tt = tile_id & 3;
    const int quad = lane >> 4, l16 = lane & 15;
    f16x4 v;
#pragma unroll
    for (int r = 0; r < 4; ++r)
      v[r] = (f16_t)tile[tq * 16 + quad * 4 + r][tt * 16 + l16];
    const size_t qb16 = (q0 >> 4) + tq, tb16 = (t0 >> 4) + tt;
    biasR[(qb16 * 128 + tb16) * 64 + lane] = v;
  }
}

// ------------- V transpose per head: VT[(bh*64+d)*ST + t] = V[(b*ST+t)*E + h*64+d] ---
__global__ __launch_bounds__(256) void vtrans_kernel(const f16_t* __restrict__ V,
                                                     f16_t* __restrict__ VT) {
  __shared__ f16_t tile[64][72];
  const int bh = blockIdx.y;
  const int b = bh >> 3, h = bh & 7;
  const int t0 = blockIdx.x * 64;
  for (int i = threadIdx.x; i < 64 * 64; i += 256) {
    const int t = i >> 6, d = i & 63;
    tile[d][t] = V[(size_t)(b * ST_ + t0 + t) * E_ + h * HD_ + d];
  }
  __syncthreads();
  for (int i = threadIdx.x; i < 64 * 64; i += 256) {
    const int d = i >> 6, t = i & 63;
    VT[(size_t)(bh * HD_ + d) * ST_ + t0 + t] = tile[d][t];
  }
}

// ------------- GEMM: C[m,n] = sum_k A[m,k] * Bt[n,k]  (128x64 tile, BK=32) -------------
// 4 waves, each wave 64x32 subtile as 4x2 frags of 16x16x32 f16 MFMA. 512 blocks -> 2/CU.
template <bool OUT_F16>
__global__ __launch_bounds__(256) void gemm_bt_kernel(const f16_t* __restrict__ A,
                                                      const f16_t* __restrict__ Bt,
                                                      void* __restrict__ Cv,
                                                      int M, int N, int K) {
  __shared__ f16_t As[128][40];
  __shared__ f16_t Bs[64][40];
  const int tid = threadIdx.x;
  const int lane = tid & 63;
  const int wave = tid >> 6;
  const int wm = (wave >> 1) * 64;
  const int wn = (wave & 1) * 32;
  const int m0 = blockIdx.y * 128;
  const int n0 = blockIdx.x * 64;
  const int l16 = lane & 15;
  const int quad = lane >> 4;
  const int r0 = tid >> 2;         // 0..63: staging row
  const int c0 = (tid & 3) * 8;    // staging col (elements)

  f32x4 acc[4][2] = {};

  const f16_t* A0 = A + (size_t)(m0 + r0) * K + c0;
  const f16_t* A1 = A + (size_t)(m0 + 64 + r0) * K + c0;
  const f16_t* B0 = Bt + (size_t)(n0 + r0) * K + c0;

  for (int k0 = 0; k0 < K; k0 += 32) {
    f16x8 a0 = ld8(A0 + k0);
    f16x8 a1 = ld8(A1 + k0);
    f16x8 b0 = ld8(B0 + k0);
    __syncthreads();  // protect previous iteration's fragment reads
    *reinterpret_cast<f16x8*>(&As[r0][c0]) = a0;
    *reinterpret_cast<f16x8*>(&As[64 + r0][c0]) = a1;
    *reinterpret_cast<f16x8*>(&Bs[r0][c0]) = b0;
    __syncthreads();
    f16x8 af[4], bfr[2];
#pragma unroll
    for (int i = 0; i < 4; ++i) af[i] = ld8(&As[wm + i * 16 + l16][quad * 8]);
#pragma unroll
    for (int j = 0; j < 2; ++j) bfr[j] = ld8(&Bs[wn + j * 16 + l16][quad * 8]);
#pragma unroll
    for (int i = 0; i < 4; ++i)
#pragma unroll
      for (int j = 0; j < 2; ++j)
        acc[i][j] = __builtin_amdgcn_mfma_f32_16x16x32_f16(af[i], bfr[j], acc[i][j], 0, 0, 0);
  }

#pragma unroll
  for (int i = 0; i < 4; ++i)
#pragma unroll
    for (int r = 0; r < 4; ++r) {
      const size_t row = (size_t)m0 + wm + i * 16 + quad * 4 + r;
#pragma unroll
      for (int j = 0; j < 2; ++j) {
        const size_t col = (size_t)n0 + wn + j * 16 + l16;
        if (OUT_F16)
          reinterpret_cast<f16_t*>(Cv)[row * (size_t)N + col] = (f16_t)acc[i][j][r];
        else
          reinterpret_cast<float*>(Cv)[row * (size_t)N + col] = acc[i][j][r];
      }
    }
}

// ------------- Flash attention: 64 q-rows/block (16/wave), T-tile 64 -------------
// K/V tiles staged in LDS (shared by all 4 waves). Bias pre-rearranged to C-frag order.
// Grid: 1024 linear, bh = id&31 (XCD-local heads), q0 = (id>>5)*64.
__global__ __launch_bounds__(256) void attn_kernel(const f16_t* __restrict__ Q,
                                                   const f16_t* __restrict__ K,
                                                   const f16_t* __restrict__ VT,
                                                   const f16x4* __restrict__ biasR,
                                                   f16_t* __restrict__ O) {
  __shared__ f16_t Ks[64][72];   // [t][d]
  __shared__ f16_t Vs[64][72];   // [d][t]
  __shared__ f16_t Ps[4][16][72];
  const int id = blockIdx.x;
  const int bh = id & 31;              // id%8 == bh%8 -> same-head blocks share an XCD
  const int b = bh >> 3, h = bh & 7;
  const int q0 = (id >> 5) * 64;
  const int tid = threadIdx.x;
  const int wave = tid >> 6;
  const int lane = tid & 63;
  const int l16 = lane & 15;
  const int quad = lane >> 4;
  const int qw = q0 + wave * 16;

  // Q fragments: A[m=l16][k=quad*8+j], two K=32 chunks covering hd=64
  const f16_t* qptr = Q + (size_t)(b * SQ_ + qw + l16) * E_ + h * HD_ + quad * 8;
  const f16x8 aq0 = ld8(qptr);
  const f16x8 aq1 = ld8(qptr + 32);

  // staging: thread -> (row, 16-elem chunk)
  const int srow = tid >> 2;
  const int scol = (tid & 3) * 16;
  const f16_t* kg = K + (size_t)(b * ST_ + srow) * E_ + h * HD_ + scol;
  const f16_t* vg = VT + (size_t)(bh * HD_ + srow) * ST_ + scol;
  const f16x4* bR = biasR + (size_t)(qw >> 4) * 128 * 64 + quad * 16 + l16;

  f32x4 facc[4] = {};
  float m_i[4] = {-3.0e38f, -3.0e38f, -3.0e38f, -3.0e38f};
  float l_i[4] = {0.f, 0.f, 0.f, 0.f};
  const float scale = 0.125f;  // 1/sqrt(64)
  const float L2E = 1.44269504089f;

  for (int t0 = 0; t0 < ST_; t0 += 64) {
    const f16x8 k0 = ld8(kg + (size_t)t0 * E_);
    const f16x8 k1 = ld8(kg + (size_t)t0 * E_ + 8);
    const f16x8 v0 = ld8(vg + t0);
    const f16x8 v1 = ld8(vg + t0 + 8);
    f16x4 bfrag[4];
#pragma unroll
    for (int tt = 0; tt < 4; ++tt) bfrag[tt] = bR[(size_t)((t0 >> 4) + tt) * 64];

    __syncthreads();  // previous iteration's fragment reads done
    *reinterpret_cast<f16x8*>(&Ks[srow][scol]) = k0;
    *reinterpret_cast<f16x8*>(&Ks[srow][scol + 8]) = k1;
    *reinterpret_cast<f16x8*>(&Vs[srow][scol]) = v0;
    *reinterpret_cast<f16x8*>(&Vs[srow][scol + 8]) = v1;
    __syncthreads();

    // S = Q K^T (C-layout: row=q offset quad*4+r, col=t offset l16)
    f32x4 s[4];
#pragma unroll
    for (int tt = 0; tt < 4; ++tt) {
      const f16_t* kp = &Ks[tt * 16 + l16][quad * 8];
      f32x4 a = {};
      a = __builtin_amdgcn_mfma_f32_16x16x32_f16(aq0, ld8(kp), a, 0, 0, 0);
      a = __builtin_amdgcn_mfma_f32_16x16x32_f16(aq1, ld8(kp + 32), a, 0, 0, 0);
      s[tt] = a;
    }
#pragma unroll
    for (int tt = 0; tt < 4; ++tt)
#pragma unroll
      for (int r = 0; r < 4; ++r)
        s[tt][r] = s[tt][r] * scale + (float)bfrag[tt][r];

    // online softmax: row max over 4 frags + 16-lane butterfly
    float alpha[4];
#pragma unroll
    for (int r = 0; r < 4; ++r) {
      float mx = fmaxf(fmaxf(s[0][r], s[1][r]), fmaxf(s[2][r], s[3][r]));
      mx = fmaxf(mx, __shfl_xor(mx, 1));
      mx = fmaxf(mx, __shfl_xor(mx, 2));
      mx = fmaxf(mx, __shfl_xor(mx, 4));
      mx = fmaxf(mx, __shfl_xor(mx, 8));
      const float mnew = fmaxf(m_i[r], mx);
      alpha[r] = exp2f((m_i[r] - mnew) * L2E);
      m_i[r] = mnew;
    }
    float rs[4] = {0.f, 0.f, 0.f, 0.f};
#pragma unroll
    for (int tt = 0; tt < 4; ++tt)
#pragma unroll
      for (int r = 0; r < 4; ++r) {
        const float p = exp2f((s[tt][r] - m_i[r]) * L2E);
        rs[r] += p;
        Ps[wave][quad * 4 + r][tt * 16 + l16] = (f16_t)p;  // per-wave region: no barrier
      }
#pragma unroll
    for (int r = 0; r < 4; ++r) {
      float t = rs[r];
      t += __shfl_xor(t, 1);
      t += __shfl_xor(t, 2);
      t += __shfl_xor(t, 4);
      t += __shfl_xor(t, 8);
      l_i[r] = l_i[r] * alpha[r] + t;
#pragma unroll
      for (int j = 0; j < 4; ++j) facc[j][r] *= alpha[r];
    }
    // O += P V : A = P from LDS (A-layout), B = V from LDS Vs[d][t] (k=t contiguous)
#pragma unroll
    for (int tc = 0; tc < 2; ++tc) {
      const f16x8 ap = ld8(&Ps[wave][l16][tc * 32 + quad * 8]);
#pragma unroll
      for (int j = 0; j < 4; ++j) {
        const f16x8 bv = ld8(&Vs[j * 16 + l16][tc * 32 + quad * 8]);
        facc[j] = __builtin_amdgcn_mfma_f32_16x16x32_f16(ap, bv, facc[j], 0, 0, 0);
      }
    }
  }

#pragma unroll
  for (int r = 0; r < 4; ++r) {
    const float inv = 1.0f / l_i[r];
    f16_t* op = O + (size_t)(b * SQ_ + qw + quad * 4 + r) * E_ + h * HD_ + l16;
#pragma unroll
    for (int j = 0; j < 4; ++j) op[j * 16] = (f16_t)(facc[j][r] * inv);
  }
}

// ---------------- host launch ----------------
extern "C" void kernel_launch(void* const* d_in, const int* in_sizes, int n_in,
                              void* d_out, int out_size, void* d_ws, size_t ws_size,
                              hipStream_t stream) {
  (void)in_sizes; (void)n_in; (void)out_size; (void)ws_size;
  const float* query = (const float*)d_in[0];
  const float* target = (const float*)d_in[1];
  const float* bias = (const float*)d_in[2];
  const float* Wq = (const float*)d_in[3];
  const float* Wk = (const float*)d_in[4];
  const float* Wv = (const float*)d_in[5];
  const float* Wo = (const float*)d_in[6];

  char* ws = (char*)d_ws;
  const size_t ACT = (size_t)B_ * SQ_ * E_;                  // 4,194,304 elements
  const size_t ACT_B = ACT * sizeof(f16_t);                  // 8 MB
  const size_t BIAS_B = (size_t)SQ_ * ST_ * sizeof(f16_t);   // 8 MB
  const size_t W_B = (size_t)E_ * E_ * sizeof(f16_t);        // 512 KB

  f16_t* qb = (f16_t*)(ws);                       // query f16; reused as VT later
  f16_t* tb = (f16_t*)(ws + ACT_B);               // target f16
  f16_t* biasR = (f16_t*)(ws + 2 * ACT_B);        // bias rearranged f16
  f16_t* WqT = (f16_t*)(ws + 2 * ACT_B + BIAS_B);
  f16_t* WkT = WqT + (size_t)E_ * E_;
  f16_t* WvT = WkT + (size_t)E_ * E_;
  f16_t* WoT = WvT + (size_t)E_ * E_;
  f16_t* Qp = (f16_t*)(ws + 2 * ACT_B + BIAS_B + 4 * W_B);
  f16_t* Kp = Qp + ACT;
  f16_t* Vp = Kp + ACT;
  f16_t* VT = qb;    // qb dead after Q projection
  f16_t* attn = Vp;  // Vp dead after vtrans
  // total ws: ~50 MB

  const int n4_act = (int)(ACT / 4);
  dim3 blk(256);
  cast_f16_kernel<<<dim3((n4_act + 255) / 256), blk, 0, stream>>>(query, qb, n4_act);
  cast_f16_kernel<<<dim3((n4_act + 255) / 256), blk, 0, stream>>>(target, tb, n4_act);
  bias_rearrange_kernel<<<dim3(ST_ / 64, SQ_ / 64), blk, 0, stream>>>(bias, (f16x4*)biasR);
  dim3 wgrid(E_ / 32, E_ / 32);
  wtrans_kernel<<<wgrid, blk, 0, stream>>>(Wq, WqT);
  wtrans_kernel<<<wgrid, blk, 0, stream>>>(Wk, WkT);
  wtrans_kernel<<<wgrid, blk, 0, stream>>>(Wv, WvT);
  wtrans_kernel<<<wgrid, blk, 0, stream>>>(Wo, WoT);

  dim3 ggrid(E_ / 64, B_ * SQ_ / 128);  // (8, 64) = 512 blocks -> 2/CU
  gemm_bt_kernel<true><<<ggrid, blk, 0, stream>>>(qb, WqT, Qp, B_ * SQ_, E_, E_);
  gemm_bt_kernel<true><<<ggrid, blk, 0, stream>>>(tb, WkT, Kp, B_ * SQ_, E_, E_);
  gemm_bt_kernel<true><<<ggrid, blk, 0, stream>>>(tb, WvT, Vp, B_ * SQ_, E_, E_);

  vtrans_kernel<<<dim3(ST_ / 64, B_ * H_), blk, 0, stream>>>(Vp, VT);

  attn_kernel<<<dim3(SQ_ / 64 * B_ * H_), blk, 0, stream>>>(Qp, Kp, VT, (const f16x4*)biasR, attn);

  gemm_bt_kernel<false><<<ggrid, blk, 0, stream>>>(attn, WoT, (void*)d_out, B_ * SQ_, E_, E_);
}

// Round 3
// 250.283 us; speedup vs baseline: 1.7139x; 1.2897x over previous
//
#include <hip/hip_runtime.h>
#include <cstdint>

// Problem constants (fixed by setup_inputs)
#define B_ 4
#define SQ_ 2048
#define ST_ 2048
#define E_ 512
#define H_ 8
#define HD_ 64
#define LDQ_ (3 * E_)  // QKV buffer row stride = 1536

typedef _Float16 f16_t;
typedef _Float16 f16x8 __attribute__((ext_vector_type(8)));
typedef _Float16 f16x4 __attribute__((ext_vector_type(4)));
typedef float f32x4 __attribute__((ext_vector_type(4)));

static __device__ __forceinline__ f16x8 ld8(const f16_t* p) {
  return *reinterpret_cast<const f16x8*>(p);
}

// async global->LDS, 16B per lane (global_load_lds_dwordx4)
static __device__ __forceinline__ void gld16(const f16_t* g, f16_t* l) {
  __builtin_amdgcn_global_load_lds((const __attribute__((address_space(1))) void*)g,
                                   (__attribute__((address_space(3))) void*)l, 16, 0, 0);
}

// ---------------- fp32 -> fp16 cast (vectorized) ----------------
__global__ __launch_bounds__(256) void cast_f16_kernel(const float* __restrict__ in,
                                                       f16_t* __restrict__ out, int n4) {
  int i = blockIdx.x * 256 + threadIdx.x;
  if (i < n4) {
    float4 v = reinterpret_cast<const float4*>(in)[i];
    f16x4 o = {(f16_t)v.x, (f16_t)v.y, (f16_t)v.z, (f16_t)v.w};
    reinterpret_cast<f16x4*>(out)[i] = o;
  }
}

// ------------- weight transpose + cast: Wt[n][k] = (f16)W[k][n] -------------
__global__ __launch_bounds__(256) void wtrans_kernel(const float* __restrict__ W,
                                                     f16_t* __restrict__ Wt) {
  __shared__ float tile[32][33];
  const int tx = threadIdx.x & 31;
  const int ty = threadIdx.x >> 5;  // 0..7
  const int bx = blockIdx.x * 32;   // n block
  const int by = blockIdx.y * 32;   // k block
#pragma unroll
  for (int i = 0; i < 4; ++i)
    tile[ty + i * 8][tx] = W[(size_t)(by + ty + i * 8) * E_ + bx + tx];
  __syncthreads();
#pragma unroll
  for (int i = 0; i < 4; ++i)
    Wt[(size_t)(bx + ty + i * 8) * E_ + by + tx] = (f16_t)tile[tx][ty + i * 8];
}

// ------------- bias rearrange, TRANSPOSED C-frag order, pre-scaled by log2(e) ----
// biasRT f16x4 index: ((q>>4)*128 + (t>>4))*64 + lane, where within the 16x16 tile
// q = 16*(q>>4) + (lane&15), t = 16*(t>>4) + (lane>>4)*4 + r  (elem r)
__global__ __launch_bounds__(256) void bias_rearrangeT_kernel(const float* __restrict__ bias,
                                                              f16x4* __restrict__ biasRT) {
  __shared__ float tile[64][65];
  const int q0 = blockIdx.y * 64;
  const int t0 = blockIdx.x * 64;
  const int tid = threadIdx.x;
  for (int i = tid; i < 64 * 64; i += 256) {
    const int q = i >> 6, t = i & 63;
    tile[q][t] = bias[(size_t)(q0 + q) * ST_ + t0 + t];
  }
  __syncthreads();
#pragma unroll
  for (int s = 0; s < 4; ++s) {
    const int slot = s * 256 + tid;        // 0..1023
    const int tile_id = slot >> 6;         // 0..15
    const int lane = slot & 63;
    const int tq = tile_id >> 2, tt = tile_id & 3;
    const int quad = lane >> 4, l16 = lane & 15;
    f16x4 v;
#pragma unroll
    for (int r = 0; r < 4; ++r)
      v[r] = (f16_t)(tile[tq * 16 + l16][tt * 16 + quad * 4 + r] * 1.44269504089f);
    const size_t qb16 = (q0 >> 4) + tq, tb16 = (t0 >> 4) + tt;
    biasRT[(qb16 * 128 + tb16) * 64 + lane] = v;
  }
}

// ------------- V transpose per head from QKV: VT[(bh*64+d)*ST + t] -------------
// Vsrc = QKV + 2*E_ (V columns), row stride LDQ_
__global__ __launch_bounds__(256) void vtrans_kernel(const f16_t* __restrict__ Vsrc,
                                                     f16_t* __restrict__ VT) {
  __shared__ f16_t tile[64][72];
  const int bh = blockIdx.y;
  const int b = bh >> 3, h = bh & 7;
  const int t0 = blockIdx.x * 64;
  for (int i = threadIdx.x; i < 64 * 64; i += 256) {
    const int t = i >> 6, d = i & 63;
    tile[d][t] = Vsrc[(size_t)(b * ST_ + t0 + t) * LDQ_ + h * HD_ + d];
  }
  __syncthreads();
  for (int i = threadIdx.x; i < 64 * 64; i += 256) {
    const int d = i >> 6, t = i & 63;
    VT[(size_t)(bh * HD_ + d) * ST_ + t0 + t] = tile[d][t];
  }
}

// ------------- m97-style GEMM: C[m,n] = sum_k A[m,k] * Bt[n,k] -------------
// 128x128 tile, BK=32, global_load_lds width-16 staging, unpadded LDS.
// A source selected per n-block: n0 < E_ -> Aq (query), else Akv (target).
template <bool OUT_F16>
__global__ __launch_bounds__(256) void gemm_bt2_kernel(const f16_t* __restrict__ Aq,
                                                       const f16_t* __restrict__ Akv,
                                                       const f16_t* __restrict__ Bt,
                                                       void* __restrict__ Cv,
                                                       int K, int ldc) {
  __shared__ f16_t As[128 * 32];
  __shared__ f16_t Bs[128 * 32];
  const int tid = threadIdx.x;
  const int lane = tid & 63;
  const int wave = tid >> 6;
  const int wm = (wave >> 1) * 64;
  const int wn = (wave & 1) * 64;
  const int m0 = blockIdx.y * 128;
  const int n0 = blockIdx.x * 128;
  const int l16 = lane & 15;
  const int quad = lane >> 4;
  const f16_t* A = (n0 < E_) ? Aq : Akv;

  f32x4 acc[4][4] = {};

  // staging: wave w covers 16-row chunks {w, w+4}; lane -> row=chunk*16+lane/4, col=(lane&3)*8
  const int r0 = wave * 16 + (lane >> 2);
  const int r1 = (wave + 4) * 16 + (lane >> 2);
  const int c0 = (lane & 3) * 8;
  const f16_t* Ag0 = A + (size_t)(m0 + r0) * K + c0;
  const f16_t* Ag1 = A + (size_t)(m0 + r1) * K + c0;
  const f16_t* Bg0 = Bt + (size_t)(n0 + r0) * K + c0;
  const f16_t* Bg1 = Bt + (size_t)(n0 + r1) * K + c0;
  f16_t* Al0 = &As[wave * 512 + lane * 8];
  f16_t* Al1 = &As[(wave + 4) * 512 + lane * 8];
  f16_t* Bl0 = &Bs[wave * 512 + lane * 8];
  f16_t* Bl1 = &Bs[(wave + 4) * 512 + lane * 8];

  for (int k0 = 0; k0 < K; k0 += 32) {
    __syncthreads();  // previous iteration's fragment reads complete
    gld16(Ag0 + k0, Al0);
    gld16(Ag1 + k0, Al1);
    gld16(Bg0 + k0, Bl0);
    gld16(Bg1 + k0, Bl1);
    __syncthreads();  // drains vmcnt: staged data visible
    f16x8 af[4], bfr[4];
#pragma unroll
    for (int i = 0; i < 4; ++i) af[i] = ld8(&As[(wm + i * 16 + l16) * 32 + quad * 8]);
#pragma unroll
    for (int j = 0; j < 4; ++j) bfr[j] = ld8(&Bs[(wn + j * 16 + l16) * 32 + quad * 8]);
#pragma unroll
    for (int i = 0; i < 4; ++i)
#pragma unroll
      for (int j = 0; j < 4; ++j)
        acc[i][j] = __builtin_amdgcn_mfma_f32_16x16x32_f16(af[i], bfr[j], acc[i][j], 0, 0, 0);
  }

#pragma unroll
  for (int i = 0; i < 4; ++i)
#pragma unroll
    for (int r = 0; r < 4; ++r) {
      const size_t row = (size_t)m0 + wm + i * 16 + quad * 4 + r;
#pragma unroll
      for (int j = 0; j < 4; ++j) {
        const size_t col = (size_t)n0 + wn + j * 16 + l16;
        if (OUT_F16)
          reinterpret_cast<f16_t*>(Cv)[row * (size_t)ldc + col] = (f16_t)acc[i][j][r];
        else
          reinterpret_cast<float*>(Cv)[row * (size_t)ldc + col] = acc[i][j][r];
      }
    }
}

// ------------- Flash attention, S^T formulation -------------
// S^T = K·Q^T via operand-swapped MFMA: lane's 16 scores all belong to q=l16.
// Softmax in log2 domain; P packed-written to LDS (b64); PV as before.
__global__ __launch_bounds__(256) void attn_kernel(const f16_t* __restrict__ QKV,
                                                   const f16_t* __restrict__ VT,
                                                   const f16x4* __restrict__ biasRT,
                                                   f16_t* __restrict__ O) {
  __shared__ f16_t Ks[64][72];   // [t][d]
  __shared__ f16_t Vs[64][72];   // [d][t]
  __shared__ f16_t Ps[4][16][72];
  const int id = blockIdx.x;
  const int bh = id & 31;              // id%8 == bh%8 -> same-head blocks share an XCD
  const int b = bh >> 3, h = bh & 7;
  const int q0 = (id >> 5) * 64;
  const int tid = threadIdx.x;
  const int wave = tid >> 6;
  const int lane = tid & 63;
  const int l16 = lane & 15;
  const int quad = lane >> 4;
  const int qw = q0 + wave * 16;

  // Q as B-operand: B[k=d=quad*8+j][n=q=l16]
  const f16_t* qptr = QKV + (size_t)(b * SQ_ + qw + l16) * LDQ_ + h * HD_ + quad * 8;
  const f16x8 bq0 = ld8(qptr);
  const f16x8 bq1 = ld8(qptr + 32);

  // staging: thread -> (row, 16-elem chunk)
  const int srow = tid >> 2;
  const int scol = (tid & 3) * 16;
  const f16_t* kg = QKV + (size_t)(b * ST_ + srow) * LDQ_ + E_ + h * HD_ + scol;
  const f16_t* vg = VT + (size_t)(bh * HD_ + srow) * ST_ + scol;
  const f16x4* bRT = biasRT + (size_t)(qw >> 4) * 128 * 64 + lane;

  // prefetch tile 0
  f16x8 nk0 = ld8(kg), nk1 = ld8(kg + 8);
  f16x8 nv0 = ld8(vg), nv1 = ld8(vg + 8);
  f16x4 nb[4];
#pragma unroll
  for (int tt = 0; tt < 4; ++tt) nb[tt] = bRT[(size_t)tt * 64];

  f32x4 facc[4] = {};
  float mL = -3.0e38f;  // running max, log2 domain
  float l_i = 0.f;
  const float QS = 0.125f * 1.44269504089f;  // scale * log2(e)

  for (int t0 = 0; t0 < ST_; t0 += 64) {
    __syncthreads();  // previous iteration's fragment reads done
    *reinterpret_cast<f16x8*>(&Ks[srow][scol]) = nk0;
    *reinterpret_cast<f16x8*>(&Ks[srow][scol + 8]) = nk1;
    *reinterpret_cast<f16x8*>(&Vs[srow][scol]) = nv0;
    *reinterpret_cast<f16x8*>(&Vs[srow][scol + 8]) = nv1;
    f16x4 cb[4];
#pragma unroll
    for (int tt = 0; tt < 4; ++tt) cb[tt] = nb[tt];
    __syncthreads();

    // prefetch next tile into registers (overlaps with compute below)
    if (t0 + 64 < ST_) {
      const size_t go = (size_t)(t0 + 64) * LDQ_;
      nk0 = ld8(kg + go);
      nk1 = ld8(kg + go + 8);
      nv0 = ld8(vg + t0 + 64);
      nv1 = ld8(vg + t0 + 72);
      const f16x4* bn = bRT + (size_t)((t0 + 64) >> 4) * 64;
#pragma unroll
      for (int tt = 0; tt < 4; ++tt) nb[tt] = bn[(size_t)tt * 64];
    }

    // S^T = K·Q^T: C row = t offset (quad*4+r), col = q = l16
    f32x4 s[4];
#pragma unroll
    for (int tt = 0; tt < 4; ++tt) {
      const f16_t* kp = &Ks[tt * 16 + l16][quad * 8];
      f32x4 a = {};
      a = __builtin_amdgcn_mfma_f32_16x16x32_f16(ld8(kp), bq0, a, 0, 0, 0);
      a = __builtin_amdgcn_mfma_f32_16x16x32_f16(ld8(kp + 32), bq1, a, 0, 0, 0);
      s[tt] = a;
    }
    // log2-domain scores: s*scale*log2e + bias*log2e
#pragma unroll
    for (int tt = 0; tt < 4; ++tt)
#pragma unroll
      for (int r = 0; r < 4; ++r)
        s[tt][r] = s[tt][r] * QS + (float)cb[tt][r];

    // tile max: 16 in-lane + cross-quad (t spans regs x quads; q=l16 fixed)
    float tmax = fmaxf(fmaxf(s[0][0], s[0][1]), fmaxf(s[0][2], s[0][3]));
#pragma unroll
    for (int tt = 1; tt < 4; ++tt)
      tmax = fmaxf(tmax, fmaxf(fmaxf(s[tt][0], s[tt][1]), fmaxf(s[tt][2], s[tt][3])));
    tmax = fmaxf(tmax, __shfl_xor(tmax, 16));
    tmax = fmaxf(tmax, __shfl_xor(tmax, 32));
    const float mnew = fmaxf(mL, tmax);
    const float alpha = exp2f(mL - mnew);
    mL = mnew;

    float rsum = 0.f;
#pragma unroll
    for (int tt = 0; tt < 4; ++tt) {
      f16x4 pk;
#pragma unroll
      for (int r = 0; r < 4; ++r) {
        const float pv = exp2f(s[tt][r] - mL);
        rsum += pv;
        pk[r] = (f16_t)pv;
      }
      // packed 8B store; per-wave region, same-wave read below -> no barrier
      *reinterpret_cast<f16x4*>(&Ps[wave][l16][tt * 16 + quad * 4]) = pk;
    }
    rsum += __shfl_xor(rsum, 16);
    rsum += __shfl_xor(rsum, 32);
    l_i = l_i * alpha + rsum;

    // broadcast alpha (per q=l16) to C-layout rows (q=quad*4+r), rescale O acc
#pragma unroll
    for (int r = 0; r < 4; ++r) {
      const float ar = __shfl(alpha, quad * 4 + r);
      facc[0][r] *= ar;
      facc[1][r] *= ar;
      facc[2][r] *= ar;
      facc[3][r] *= ar;
    }

    // O += P V : A = P from LDS (A-layout), B = V from Vs[d][t]
#pragma unroll
    for (int tc = 0; tc < 2; ++tc) {
      const f16x8 ap = ld8(&Ps[wave][l16][tc * 32 + quad * 8]);
#pragma unroll
      for (int j = 0; j < 4; ++j) {
        const f16x8 bv = ld8(&Vs[j * 16 + l16][tc * 32 + quad * 8]);
        facc[j] = __builtin_amdgcn_mfma_f32_16x16x32_f16(ap, bv, facc[j], 0, 0, 0);
      }
    }
  }

#pragma unroll
  for (int r = 0; r < 4; ++r) {
    const float lr = __shfl(l_i, quad * 4 + r);
    const float inv = 1.0f / lr;
    f16_t* op = O + (size_t)(b * SQ_ + qw + quad * 4 + r) * E_ + h * HD_ + l16;
#pragma unroll
    for (int j = 0; j < 4; ++j) op[j * 16] = (f16_t)(facc[j][r] * inv);
  }
}

// ---------------- host launch ----------------
extern "C" void kernel_launch(void* const* d_in, const int* in_sizes, int n_in,
                              void* d_out, int out_size, void* d_ws, size_t ws_size,
                              hipStream_t stream) {
  (void)in_sizes; (void)n_in; (void)out_size; (void)ws_size;
  const float* query = (const float*)d_in[0];
  const float* target = (const float*)d_in[1];
  const float* bias = (const float*)d_in[2];
  const float* Wq = (const float*)d_in[3];
  const float* Wk = (const float*)d_in[4];
  const float* Wv = (const float*)d_in[5];
  const float* Wo = (const float*)d_in[6];

  char* ws = (char*)d_ws;
  const size_t ACT = (size_t)B_ * SQ_ * E_;                  // 4,194,304 elements
  const size_t ACT_B = ACT * sizeof(f16_t);                  // 8 MB
  const size_t BIAS_B = (size_t)SQ_ * ST_ * sizeof(f16_t);   // 8 MB
  const size_t W_B = (size_t)E_ * E_ * sizeof(f16_t);        // 512 KB

  f16_t* qb = (f16_t*)(ws);                        // query f16; reused as VT later
  f16_t* tb = (f16_t*)(ws + ACT_B);                // target f16; reused as attn out
  f16_t* biasRT = (f16_t*)(ws + 2 * ACT_B);        // bias rearranged/transposed f16
  f16_t* WqkvT = (f16_t*)(ws + 2 * ACT_B + BIAS_B);  // [1536][512]
  f16_t* WoT = WqkvT + 3 * (size_t)E_ * E_;
  f16_t* QKV = (f16_t*)(ws + 2 * ACT_B + BIAS_B + 4 * W_B);  // [8192][1536]
  f16_t* VT = qb;     // qb dead after gemm_qkv
  f16_t* attn = tb;   // tb dead after gemm_qkv
  // total ws: ~50 MB

  const int n4_act = (int)(ACT / 4);
  dim3 blk(256);
  cast_f16_kernel<<<dim3((n4_act + 255) / 256), blk, 0, stream>>>(query, qb, n4_act);
  cast_f16_kernel<<<dim3((n4_act + 255) / 256), blk, 0, stream>>>(target, tb, n4_act);
  bias_rearrangeT_kernel<<<dim3(ST_ / 64, SQ_ / 64), blk, 0, stream>>>(bias, (f16x4*)biasRT);
  dim3 wgrid(E_ / 32, E_ / 32);
  wtrans_kernel<<<wgrid, blk, 0, stream>>>(Wq, WqkvT);
  wtrans_kernel<<<wgrid, blk, 0, stream>>>(Wk, WqkvT + (size_t)E_ * E_);
  wtrans_kernel<<<wgrid, blk, 0, stream>>>(Wv, WqkvT + 2 * (size_t)E_ * E_);
  wtrans_kernel<<<wgrid, blk, 0, stream>>>(Wo, WoT);

  // fused QKV projection: N=1536, A = query-f16 for n<512 else target-f16
  gemm_bt2_kernel<true><<<dim3(3 * E_ / 128, B_ * SQ_ / 128), blk, 0, stream>>>(
      qb, tb, WqkvT, QKV, E_, LDQ_);

  vtrans_kernel<<<dim3(ST_ / 64, B_ * H_), blk, 0, stream>>>(QKV + 2 * E_, VT);

  attn_kernel<<<dim3(SQ_ / 64 * B_ * H_), blk, 0, stream>>>(QKV, VT, (const f16x4*)biasRT, attn);

  // output projection -> fp32 d_out
  gemm_bt2_kernel<false><<<dim3(E_ / 128, B_ * SQ_ / 128), blk, 0, stream>>>(
      attn, attn, WoT, (void*)d_out, E_, E_);
}